// Round 1
// baseline (566.665 us; speedup 1.0000x reference)
//
#include <hip/hip_runtime.h>

// Problem constants (match reference)
#define D     4
#define MUL   16
#define S0    8
#define S1    8
#define SOUT  8
#define NP3   8
#define NP4   4

#define EPB   16          // edges per block
#define TPB   256         // EPB * MUL
#define NW    (NP3*16 + NP4*16)   // 192 weight entries per edge
#define WPAD  193         // padded LDS row stride (193 % 32 == 1 -> conflict-free)

__device__ __forceinline__ float4 sel8(const float4 (&a)[8], int s) {
    // s is wave-uniform (path metadata) -> uniform branches, constant reg indices
    switch (s & 7) {
        case 0: return a[0];
        case 1: return a[1];
        case 2: return a[2];
        case 3: return a[3];
        case 4: return a[4];
        case 5: return a[5];
        case 6: return a[6];
        default: return a[7];
    }
}

#define ADDC(idx) acc[idx].x += cx; acc[idx].y += cy; acc[idx].z += cz; acc[idx].w += cw; break;
__device__ __forceinline__ void addsel8(float4 (&acc)[8], int s,
                                        float cx, float cy, float cz, float cw) {
    switch (s & 7) {
        case 0: ADDC(0)
        case 1: ADDC(1)
        case 2: ADDC(2)
        case 3: ADDC(3)
        case 4: ADDC(4)
        case 5: ADDC(5)
        case 6: ADDC(6)
        default: ADDC(7)
    }
}

__global__ __launch_bounds__(TPB)
void tp_fused_kernel(const float* __restrict__ x0,
                     const int*   __restrict__ i0,
                     const float* __restrict__ x1,
                     const float* __restrict__ C3,
                     const float* __restrict__ C4,
                     const int*   __restrict__ p3,
                     const int*   __restrict__ p4,
                     float*       __restrict__ out,
                     int E)
{
    __shared__ float x1t[EPB][33];     // x1 row per edge, padded
    __shared__ float Wt[EPB][WPAD];    // per-edge fused weights: W3 (128) then W4 (64)
    __shared__ int   pp3[NP3 * 3];
    __shared__ int   pp4[NP4 * 4];

    const int tid = threadIdx.x;
    const int eL  = tid >> 4;    // 0..15 local edge
    const int u   = tid & 15;    // 0..15 mul channel
    const long e  = (long)blockIdx.x * EPB + eL;
    const bool valid = (e < (long)E);

    if (tid < NP3 * 3)                 pp3[tid]      = p3[tid];
    else if (tid < NP3 * 3 + NP4 * 4)  pp4[tid - NP3 * 3] = p4[tid - NP3 * 3];

    // stage x1 row: 32 floats per edge, 2 per thread (coalesced)
    if (valid) {
        const float* xr = x1 + e * (S1 * D);
        x1t[eL][u]      = xr[u];
        x1t[eL][u + 16] = xr[u + 16];
    }
    __syncthreads();

    // cooperatively build per-edge weight matrices: 192 entries / 16 threads = 12 each
    if (valid) {
        #pragma unroll
        for (int t = 0; t < NW / MUL; ++t) {
            const int idx = u * (NW / MUL) + t;
            float w;
            if (idx < NP3 * 16) {
                // W3[p][i][k] = sum_j b[j] * C3[p][i][j][k]
                const int p = idx >> 4, rem = idx & 15;
                const int i = rem >> 2, k = rem & 3;
                const float* b  = &x1t[eL][pp3[p * 3 + 1] * D];
                const float* c3 = C3 + (p * D + i) * D * D + k;   // j-stride = D
                w = b[0] * c3[0] + b[1] * c3[D] + b[2] * c3[2 * D] + b[3] * c3[3 * D];
            } else {
                // W4[p][i][m] = sum_{j,k} b[j] c[k] * C4[p][i][j][k][m]
                const int idx4 = idx - NP3 * 16;
                const int p = idx4 >> 4, rem = idx4 & 15;
                const int i = rem >> 2, m = rem & 3;
                const float* b  = &x1t[eL][pp4[p * 4 + 1] * D];
                const float* c  = &x1t[eL][pp4[p * 4 + 2] * D];
                const float* c4 = C4 + (p * D + i) * D * D * D + m; // j-stride D*D, k-stride D
                float s = 0.f;
                #pragma unroll
                for (int j = 0; j < D; ++j) {
                    #pragma unroll
                    for (int k = 0; k < D; ++k)
                        s += b[j] * c[k] * c4[(j * D + k) * D];
                }
                w = s;
            }
            Wt[eL][idx] = w;
        }
    }
    __syncthreads();

    if (!valid) return;

    // gather x0 row fragments for this u: 8 float4, coalesced across the 16 u-lanes
    const float4* ar = (const float4*)(x0 + (long)i0[e] * (S0 * MUL * D));
    float4 a[S0];
    #pragma unroll
    for (int s = 0; s < S0; ++s) a[s] = ar[s * MUL + u];

    float4 acc[SOUT];
    #pragma unroll
    for (int s = 0; s < SOUT; ++s) acc[s] = make_float4(0.f, 0.f, 0.f, 0.f);

    const float* W = Wt[eL];

    // 3-input paths
    #pragma unroll
    for (int p = 0; p < NP3; ++p) {
        const int s0s  = pp3[p * 3 + 0];
        const int outs = pp3[p * 3 + 2];
        const float4 av = sel8(a, s0s);
        const float* w = W + (p << 4);           // w[i*4+k]
        float cx = av.x * w[0] + av.y * w[4] + av.z * w[8]  + av.w * w[12];
        float cy = av.x * w[1] + av.y * w[5] + av.z * w[9]  + av.w * w[13];
        float cz = av.x * w[2] + av.y * w[6] + av.z * w[10] + av.w * w[14];
        float cw = av.x * w[3] + av.y * w[7] + av.z * w[11] + av.w * w[15];
        addsel8(acc, outs, cx, cy, cz, cw);
    }
    // 4-input paths (b,c already folded into W4)
    #pragma unroll
    for (int p = 0; p < NP4; ++p) {
        const int s0s  = pp4[p * 4 + 0];
        const int outs = pp4[p * 4 + 3];
        const float4 av = sel8(a, s0s);
        const float* w = W + NP3 * 16 + (p << 4); // w[i*4+m]
        float cx = av.x * w[0] + av.y * w[4] + av.z * w[8]  + av.w * w[12];
        float cy = av.x * w[1] + av.y * w[5] + av.z * w[9]  + av.w * w[13];
        float cz = av.x * w[2] + av.y * w[6] + av.z * w[10] + av.w * w[14];
        float cw = av.x * w[3] + av.y * w[7] + av.z * w[11] + av.w * w[15];
        addsel8(acc, outs, cx, cy, cz, cw);
    }

    // store: 8 float4 per thread, coalesced across u-lanes
    float4* outr = (float4*)(out + e * (SOUT * MUL * D));
    #pragma unroll
    for (int s = 0; s < SOUT; ++s) outr[s * MUL + u] = acc[s];
}

extern "C" void kernel_launch(void* const* d_in, const int* in_sizes, int n_in,
                              void* d_out, int out_size, void* d_ws, size_t ws_size,
                              hipStream_t stream) {
    const float* x0 = (const float*)d_in[0];
    const int*   i0 = (const int*)  d_in[1];
    const float* x1 = (const float*)d_in[2];
    const float* C3 = (const float*)d_in[3];
    const float* C4 = (const float*)d_in[4];
    const int*   p3 = (const int*)  d_in[5];
    const int*   p4 = (const int*)  d_in[6];
    float* out = (float*)d_out;

    const int E = in_sizes[1];                 // i0 has E elements
    const int blocks = (E + EPB - 1) / EPB;
    tp_fused_kernel<<<blocks, TPB, 0, stream>>>(x0, i0, x1, C3, C4, p3, p4, out, E);
}

// Round 2
// 420.955 us; speedup vs baseline: 1.3461x; 1.3461x over previous
//
#include <hip/hip_runtime.h>

// Problem constants (match reference)
#define D     4
#define MUL   16
#define S0    8
#define S1    8
#define SOUT  8
#define NP3   8
#define NP4   4

#define EPB   16          // edges per block (4 per wave)
#define TPB   256
// Wt row stride per edge: 192 entries + 8 pad = 200 floats = 800 B.
// 800 B is 16B-aligned (ds_*_b128 ok); 200 % 32 == 8 -> the 4 edges of a wave
// start 8 banks apart -> b128 broadcast reads are conflict-free.
#define WSTRIDE 200

typedef float vf4 __attribute__((ext_vector_type(4)));

// Wave-scope LDS ordering: producers and consumers of each Wt row are the SAME
// wave (edge eL's 16 threads all live in wave eL>>2), and DS ops from one wave
// execute in order. We only need to stop the compiler from reordering.
__device__ __forceinline__ void wave_lds_fence() {
    __builtin_amdgcn_fence(__ATOMIC_RELEASE, "wavefront");
    __builtin_amdgcn_wave_barrier();
    __builtin_amdgcn_fence(__ATOMIC_ACQUIRE, "wavefront");
}

__device__ __forceinline__ float4 sel8(const float4 (&a)[8], int s) {
    // s comes from SGPR-resident path metadata -> uniform branch tree
    switch (s & 7) {
        case 0: return a[0];
        case 1: return a[1];
        case 2: return a[2];
        case 3: return a[3];
        case 4: return a[4];
        case 5: return a[5];
        case 6: return a[6];
        default: return a[7];
    }
}

#define ADDC(idx) acc[idx].x += cv.x; acc[idx].y += cv.y; acc[idx].z += cv.z; acc[idx].w += cv.w; break;
__device__ __forceinline__ void addsel8(float4 (&acc)[8], int s, float4 cv) {
    switch (s & 7) {
        case 0: ADDC(0)
        case 1: ADDC(1)
        case 2: ADDC(2)
        case 3: ADDC(3)
        case 4: ADDC(4)
        case 5: ADDC(5)
        case 6: ADDC(6)
        default: ADDC(7)
    }
}

__global__ __launch_bounds__(TPB)
void tp_fused_kernel(const float* __restrict__ x0,
                     const int*   __restrict__ i0,
                     const float* __restrict__ x1,
                     const float* __restrict__ C3,
                     const float* __restrict__ C4,
                     const int*   __restrict__ p3,
                     const int*   __restrict__ p4,
                     float*       __restrict__ out,
                     int E)
{
    __shared__ float Wt[EPB * WSTRIDE];

    const int tid = threadIdx.x;
    const int eL  = tid >> 4;        // local edge 0..15
    const int u   = tid & 15;        // mul channel 0..15
    const long e  = (long)blockIdx.x * EPB + eL;
    const bool ev = (e < (long)E);
    const long ec = ev ? e : (long)(E - 1);

    // ---------- issue the long-latency gather chain FIRST ----------
    const int row = i0[ec];
    const float4* ar = (const float4*)(x0 + (long)row * (S0 * MUL * D));
    float4 a[S0];
    #pragma unroll
    for (int s = 0; s < S0; ++s) a[s] = ar[s * MUL + u];

    // ---------- path metadata: uniform addresses -> s_load into SGPRs ----------
    int q3s1[NP3], q3s0[NP3], q3so[NP3];
    #pragma unroll
    for (int p = 0; p < NP3; ++p) {
        q3s0[p] = p3[p * 3 + 0];
        q3s1[p] = p3[p * 3 + 1];
        q3so[p] = p3[p * 3 + 2];
    }
    int q4s0[NP4], q4s1[NP4], q4s2[NP4], q4so[NP4];
    #pragma unroll
    for (int p = 0; p < NP4; ++p) {
        q4s0[p] = p4[p * 4 + 0];
        q4s1[p] = p4[p * 4 + 1];
        q4s2[p] = p4[p * 4 + 2];
        q4so[p] = p4[p * 4 + 3];
    }

    // ---------- per-edge weight matrices (overlaps gather latency) ----------
    // Lane u computes entry r=u of each path's 16-entry (i x k) weight block.
    const float* x1r = x1 + ec * (S1 * D);
    const int iu = u >> 2, ku = u & 3;

    float* wr = &Wt[eL * WSTRIDE];

    #pragma unroll
    for (int p = 0; p < NP3; ++p) {
        // b is uniform per edge: broadcast float4 load (L1-hot after first touch)
        const float4 b = *(const float4*)(x1r + q3s1[p] * D);
        const float* c3 = C3 + p * 64 + iu * 16 + ku;   // + j*4
        wr[p * 16 + u] = b.x * c3[0] + b.y * c3[4] + b.z * c3[8] + b.w * c3[12];
    }
    #pragma unroll
    for (int p = 0; p < NP4; ++p) {
        const float4 b = *(const float4*)(x1r + q4s1[p] * D);
        const float4 c = *(const float4*)(x1r + q4s2[p] * D);
        const float* c4 = C4 + p * 256 + iu * 64 + ku;  // + j*16 + k*4
        float s = 0.f;
        const float bj[4] = {b.x, b.y, b.z, b.w};
        const float ck[4] = {c.x, c.y, c.z, c.w};
        #pragma unroll
        for (int j = 0; j < 4; ++j) {
            #pragma unroll
            for (int k = 0; k < 4; ++k)
                s += bj[j] * ck[k] * c4[j * 16 + k * 4];
        }
        wr[128 + p * 16 + u] = s;
    }

    wave_lds_fence();   // same-wave producers/consumers; no s_barrier, no vmcnt drain

    // ---------- contributions ----------
    float4 acc[SOUT];
    #pragma unroll
    for (int s = 0; s < SOUT; ++s) acc[s] = make_float4(0.f, 0.f, 0.f, 0.f);

    #pragma unroll
    for (int p = 0; p < NP3 + NP4; ++p) {
        const int s0s = (p < NP3) ? q3s0[p] : q4s0[p - NP3];
        const int os  = (p < NP3) ? q3so[p] : q4so[p - NP3];
        const float4 av = sel8(a, s0s);     // waits on gather (issued at top)
        // W row: 16 floats, 16B-aligned -> 4x ds_read_b128, conflict-free
        const float4 w0 = *(const float4*)(wr + p * 16 + 0);
        const float4 w1 = *(const float4*)(wr + p * 16 + 4);
        const float4 w2 = *(const float4*)(wr + p * 16 + 8);
        const float4 w3v = *(const float4*)(wr + p * 16 + 12);
        float4 cv;
        cv.x = av.x * w0.x + av.y * w1.x + av.z * w2.x + av.w * w3v.x;
        cv.y = av.x * w0.y + av.y * w1.y + av.z * w2.y + av.w * w3v.y;
        cv.z = av.x * w0.z + av.y * w1.z + av.z * w2.z + av.w * w3v.z;
        cv.w = av.x * w0.w + av.y * w1.w + av.z * w2.w + av.w * w3v.w;
        addsel8(acc, os, cv);
    }

    // ---------- streaming store (nontemporal: don't evict x0 from L2) ----------
    if (ev) {
        float* o = out + e * (SOUT * MUL * D);
        #pragma unroll
        for (int s = 0; s < SOUT; ++s) {
            vf4 v = { acc[s].x, acc[s].y, acc[s].z, acc[s].w };
            __builtin_nontemporal_store(v, (vf4*)(o + (s * MUL + u) * 4));
        }
    }
}

extern "C" void kernel_launch(void* const* d_in, const int* in_sizes, int n_in,
                              void* d_out, int out_size, void* d_ws, size_t ws_size,
                              hipStream_t stream) {
    const float* x0 = (const float*)d_in[0];
    const int*   i0 = (const int*)  d_in[1];
    const float* x1 = (const float*)d_in[2];
    const float* C3 = (const float*)d_in[3];
    const float* C4 = (const float*)d_in[4];
    const int*   p3 = (const int*)  d_in[5];
    const int*   p4 = (const int*)  d_in[6];
    float* out = (float*)d_out;

    const int E = in_sizes[1];                 // i0 has E elements
    const int blocks = (E + EPB - 1) / EPB;
    tp_fused_kernel<<<blocks, TPB, 0, stream>>>(x0, i0, x1, C3, C4, p3, p4, out, E);
}